// Round 4
// baseline (4579.556 us; speedup 1.0000x reference)
//
#include <hip/hip_runtime.h>

namespace {

constexpr int BATCH = 32768;
constexpr int TSTEPS = 28;

__device__ __forceinline__ float bpermf(int idx, float v) {
    return __int_as_float(__builtin_amdgcn_ds_bpermute(idx, __float_as_int(v)));
}

// DPP quad_perm shuffles (VALU-pipe, full rate)
constexpr int XOR1 = 0xB1;  // quad_perm [1,0,3,2]  -> lane ^ 1
constexpr int XOR2 = 0x4E;  // quad_perm [2,3,0,1]  -> lane ^ 2

template <int CTRL>
__device__ __forceinline__ float dppf(float v) {
    return __int_as_float(__builtin_amdgcn_mov_dpp(__float_as_int(v), CTRL, 0xF, 0xF, true));
}

__device__ __forceinline__ float exp2f_fast(float x) { return __builtin_amdgcn_exp2f(x); }
__device__ __forceinline__ float rcpf_fast(float x) { return __builtin_amdgcn_rcpf(x); }

__device__ __forceinline__ float tanhf_fast(float x) {
    float e = exp2f_fast(x * 2.885390081777927f);
    return 1.0f - 2.0f * rcpf_fast(1.0f + e);
}
__device__ __forceinline__ float sigmf_fast(float x) {
    float e = exp2f_fast(x * -1.4426950408889634f);
    return rcpf_fast(1.0f + e);
}

// Lane decomposition (16 lanes per batch element):
//   q  = lane bits {0,1}  : column-block (cols 8q..8q+7) / reduce dimension (DPP quads)
//   e  = lane bits {2,4}  : element-within-wave (4 elements per wave)
//   p  = lane bits {3,5}  : row-block (rows 8p..8p+7)
// Lane (p,q) holds W-block rows 8p+(j^off), cols 8q..8q+7 in registers; row perm
// off = (q0<<1)|(q1<<2) makes the XOR reduce-scatter placement-free: after rounds
// (xor2, xor1), P[0],P[1] hold full sums for components 2*(4p+q)+{0,1}.
//
// amdgpu_waves_per_eu(2,2): pin allocator budget to 256 VGPRs (512-reg pool / 2).
// launch_bounds(256,2) alone caps at 256 but the backend still TARGETS 4 waves/EU
// -> 128 regs + scratch spills (r1/r3: 8.9 GB FETCH, 0.9 GB WRITE of spill traffic).
__global__ __launch_bounds__(256) __attribute__((amdgpu_waves_per_eu(2, 2)))
void node_kernel(
    const float* __restrict__ g_inputs, const float* __restrict__ g_h0,
    const float* __restrict__ g_Wih, const float* __restrict__ g_Whh,
    const float* __restrict__ g_bih, const float* __restrict__ g_bhh,
    const float* __restrict__ g_W1, const float* __restrict__ g_b1,
    const float* __restrict__ g_W2, const float* __restrict__ g_b2,
    float* __restrict__ g_out)
{
    __shared__ float sWih[96 * 34];   // stride 34: 2-way-only bank aliasing (free)
    __shared__ float sWhh[96 * 34];

    const int tid = threadIdx.x;
    for (int i = tid; i < 96 * 32; i += 256) {
        int r = i >> 5, c = i & 31;
        sWih[r * 34 + c] = g_Wih[i];
        sWhh[r * 34 + c] = g_Whh[i];
    }
    __syncthreads();

    const int lane = tid & 63;
    const int wid = tid >> 6;
    const int q = lane & 3;
    const int q0 = q & 1, q1 = (q >> 1) & 1;
    const int p = ((lane >> 3) & 1) | (((lane >> 5) & 1) << 1);
    const int eloc = ((lane >> 2) & 1) | (((lane >> 4) & 1) << 1);
    const int elem = blockIdx.x * 16 + wid * 4 + eloc;
    const int off = (q0 << 1) | (q1 << 2);
    const int comp0 = ((p << 2) | q) << 1;   // owned components comp0, comp0+1

    // bpermute byte-indices: component 8q+2n+i lives on rank 4q+n
    int idx[4];
    {
        const int ebits = lane & 0x14;
        #pragma unroll
        for (int n = 0; n < 4; ++n) {
            int sl = n | (q0 << 3) | (q1 << 5) | ebits;
            idx[n] = sl << 2;
        }
    }

    // ODE MLP weights: entirely in registers (8x8 block per lane, row-permuted)
    float w1[8][8], w2[8][8];
    #pragma unroll
    for (int j = 0; j < 8; ++j) {
        const int row = 8 * p + (j ^ off);
        #pragma unroll
        for (int cb = 0; cb < 8; cb += 4) {
            float4 a = *reinterpret_cast<const float4*>(&g_W1[row * 32 + 8 * q + cb]);
            w1[j][cb] = a.x; w1[j][cb + 1] = a.y; w1[j][cb + 2] = a.z; w1[j][cb + 3] = a.w;
            float4 b = *reinterpret_cast<const float4*>(&g_W2[row * 32 + 8 * q + cb]);
            w2[j][cb] = b.x; w2[j][cb + 1] = b.y; w2[j][cb + 2] = b.z; w2[j][cb + 3] = b.w;
        }
    }

    const float b1o0 = g_b1[comp0], b1o1 = g_b1[comp0 + 1];
    const float b2o0 = g_b2[comp0], b2o1 = g_b2[comp0 + 1];
    const float br0 = g_bih[comp0] + g_bhh[comp0];
    const float br1 = g_bih[comp0 + 1] + g_bhh[comp0 + 1];
    const float bz0 = g_bih[32 + comp0] + g_bhh[32 + comp0];
    const float bz1 = g_bih[32 + comp0 + 1] + g_bhh[32 + comp0 + 1];
    const float bin0 = g_bih[64 + comp0], bin1 = g_bih[64 + comp0 + 1];
    const float bhn0 = g_bhh[64 + comp0], bhn1 = g_bhh[64 + comp0 + 1];

    float y0, y1;  // owned 2 components of hidden state
    {
        float2 h = *reinterpret_cast<const float2*>(&g_h0[(size_t)elem * 32 + comp0]);
        y0 = h.x; y1 = h.y;
    }

    auto gather8 = [&](float v0, float v1, float (&in)[8]) {
        #pragma unroll
        for (int n = 0; n < 4; ++n) {
            in[2 * n]     = bpermf(idx[n], v0);
            in[2 * n + 1] = bpermf(idx[n], v1);
        }
    };

    // XOR reduce-scatter over q (placement-free thanks to row perm `off`)
    auto reduceP = [&](float (&P)[8]) {
        P[0] += dppf<XOR2>(P[4]);
        P[1] += dppf<XOR2>(P[5]);
        P[2] += dppf<XOR2>(P[6]);
        P[3] += dppf<XOR2>(P[7]);
        P[0] += dppf<XOR1>(P[2]);
        P[1] += dppf<XOR1>(P[3]);
    };

    auto layer = [&](const float (&w)[8][8], const float (&in)[8], float& o0, float& o1) {
        float P[8];
        #pragma unroll
        for (int j = 0; j < 8; ++j) {
            float s = w[j][0] * in[0];
            #pragma unroll
            for (int cc = 1; cc < 8; ++cc) s = fmaf(w[j][cc], in[cc], s);
            P[j] = s;
        }
        reduceP(P);
        o0 = P[0]; o1 = P[1];
    };

    auto rhs = [&](float v0, float v1, float& k0, float& k1) {
        float in[8];
        gather8(v0, v1, in);
        float t0, t1;
        layer(w1, in, t0, t1);
        t0 = tanhf_fast(t0 + b1o0);
        t1 = tanhf_fast(t1 + b1o1);
        gather8(t0, t1, in);
        layer(w2, in, k0, k1);
        k0 += b2o0; k1 += b2o1;
    };

    auto rk4 = [&](float dt) {
        const float hdt = 0.5f * dt;
        const float sdt = dt * (1.0f / 6.0f);
        #pragma unroll 1
        for (int s = 0; s < 10; ++s) {
            float k0, k1, a0, a1, v0, v1;
            rhs(y0, y1, k0, k1);
            a0 = k0; a1 = k1;
            v0 = fmaf(hdt, k0, y0); v1 = fmaf(hdt, k1, y1);
            rhs(v0, v1, k0, k1);
            a0 = fmaf(2.0f, k0, a0); a1 = fmaf(2.0f, k1, a1);
            v0 = fmaf(hdt, k0, y0); v1 = fmaf(hdt, k1, y1);
            rhs(v0, v1, k0, k1);
            a0 = fmaf(2.0f, k0, a0); a1 = fmaf(2.0f, k1, a1);
            v0 = fmaf(dt, k0, y0); v1 = fmaf(dt, k1, y1);
            rhs(v0, v1, k0, k1);
            a0 += k0; a1 += k1;
            y0 = fmaf(sdt, a0, y0); y1 = fmaf(sdt, a1, y1);
        }
    };

    // One gate's (Wih.x + Whh.h) dot for this lane's 8 permuted rows; reduce
    // to the 2 owned components. gofs = row offset of the gate (0 / 32 / 64).
    auto gate_dot2 = [&](int gofs, const float (&xin)[8], const float (&hin)[8],
                         float& o0, float& o1) {
        float P[8];
        #pragma unroll
        for (int j = 0; j < 8; ++j) {
            const int row = gofs + 8 * p + (j ^ off);
            const float* wi = &sWih[row * 34 + 8 * q];
            const float* wh = &sWhh[row * 34 + 8 * q];
            float s = 0.f;
            #pragma unroll
            for (int cc = 0; cc < 8; cc += 2) {
                float2 ai = *reinterpret_cast<const float2*>(wi + cc);
                float2 ah = *reinterpret_cast<const float2*>(wh + cc);
                s = fmaf(ai.x, xin[cc], fmaf(ai.y, xin[cc + 1], s));
                s = fmaf(ah.x, hin[cc], fmaf(ah.y, hin[cc + 1], s));
            }
            P[j] = s;
        }
        reduceP(P);
        o0 = P[0]; o1 = P[1];
    };

    // Single-matrix gate dot (for the n gate's separate x / h parts)
    auto gate_dot1 = [&](const float* smat, int gofs, const float (&vin)[8],
                         float& o0, float& o1) {
        float P[8];
        #pragma unroll
        for (int j = 0; j < 8; ++j) {
            const int row = gofs + 8 * p + (j ^ off);
            const float* wr = &smat[row * 34 + 8 * q];
            float s = 0.f;
            #pragma unroll
            for (int cc = 0; cc < 8; cc += 2) {
                float2 a = *reinterpret_cast<const float2*>(wr + cc);
                s = fmaf(a.x, vin[cc], fmaf(a.y, vin[cc + 1], s));
            }
            P[j] = s;
        }
        reduceP(P);
        o0 = P[0]; o1 = P[1];
    };

    // Sequential-gate GRU: one P[8] buffer live at a time (register pressure)
    auto gru = [&](int t) {
        float xin[8];
        {
            const float* xp = &g_inputs[((size_t)elem * TSTEPS + t) * 32 + 8 * q];
            float4 xa = *reinterpret_cast<const float4*>(xp);
            float4 xb = *reinterpret_cast<const float4*>(xp + 4);
            xin[0] = xa.x; xin[1] = xa.y; xin[2] = xa.z; xin[3] = xa.w;
            xin[4] = xb.x; xin[5] = xb.y; xin[6] = xb.z; xin[7] = xb.w;
        }
        float hin[8];
        gather8(y0, y1, hin);

        float r0, r1, z0, z1, nx0, nx1, nh0, nh1;
        gate_dot2(0, xin, hin, r0, r1);
        r0 = sigmf_fast(r0 + br0);
        r1 = sigmf_fast(r1 + br1);
        gate_dot2(32, xin, hin, z0, z1);
        z0 = sigmf_fast(z0 + bz0);
        z1 = sigmf_fast(z1 + bz1);
        gate_dot1(sWih, 64, xin, nx0, nx1);
        gate_dot1(sWhh, 64, hin, nh0, nh1);
        float n0 = tanhf_fast(nx0 + bin0 + r0 * (nh0 + bhn0));
        float n1 = tanhf_fast(nx1 + bin1 + r1 * (nh1 + bhn1));
        y0 = n0 + z0 * (y0 - n0);
        y1 = n1 + z1 * (y1 - n1);
    };

    // initial integration over [0,1]
    rk4(0.1f);
    #pragma unroll 1
    for (int t = 0; t < TSTEPS - 1; ++t) {
        gru(t);
        rk4(0.1f);
    }
    gru(TSTEPS - 1);
    {
        float2 hs;
        hs.x = fmaxf(y0, 0.f); hs.y = fmaxf(y1, 0.f);
        *reinterpret_cast<float2*>(&g_out[(size_t)elem * 32 + comp0]) = hs;
    }
    rk4(1.4f);  // span 14 -> dt 1.4
    {
        float2 he;
        he.x = fmaxf(y0, 0.f); he.y = fmaxf(y1, 0.f);
        *reinterpret_cast<float2*>(&g_out[(size_t)BATCH * 32 + (size_t)elem * 32 + comp0]) = he;
    }
}

}  // namespace

extern "C" void kernel_launch(void* const* d_in, const int* in_sizes, int n_in,
                              void* d_out, int out_size, void* d_ws, size_t ws_size,
                              hipStream_t stream) {
    (void)in_sizes; (void)n_in; (void)out_size; (void)d_ws; (void)ws_size;
    const float* inputs = (const float*)d_in[0];
    const float* h0     = (const float*)d_in[1];
    const float* Wih    = (const float*)d_in[2];
    const float* Whh    = (const float*)d_in[3];
    const float* bih    = (const float*)d_in[4];
    const float* bhh    = (const float*)d_in[5];
    const float* W1     = (const float*)d_in[6];
    const float* b1     = (const float*)d_in[7];
    const float* W2     = (const float*)d_in[8];
    const float* b2     = (const float*)d_in[9];
    float* out = (float*)d_out;

    dim3 grid(BATCH / 16);   // 16 elements per 256-thread block (16 lanes/element)
    dim3 block(256);
    hipLaunchKernelGGL(node_kernel, grid, block, 0, stream,
                       inputs, h0, Wih, Whh, bih, bhh, W1, b1, W2, b2, out);
}

// Round 5
// 4187.999 us; speedup vs baseline: 1.0935x; 1.0935x over previous
//
#include <hip/hip_runtime.h>

namespace {

constexpr int BATCH = 32768;
constexpr int TSTEPS = 28;

__device__ __forceinline__ float bpermf(int idx, float v) {
    return __int_as_float(__builtin_amdgcn_ds_bpermute(idx, __float_as_int(v)));
}

// DPP quad_perm shuffles (VALU-pipe, full rate)
constexpr int XOR1 = 0xB1;  // quad_perm [1,0,3,2]  -> lane ^ 1
constexpr int XOR2 = 0x4E;  // quad_perm [2,3,0,1]  -> lane ^ 2

template <int CTRL>
__device__ __forceinline__ float dppf(float v) {
    return __int_as_float(__builtin_amdgcn_mov_dpp(__float_as_int(v), CTRL, 0xF, 0xF, true));
}

__device__ __forceinline__ float exp2f_fast(float x) { return __builtin_amdgcn_exp2f(x); }
__device__ __forceinline__ float rcpf_fast(float x) { return __builtin_amdgcn_rcpf(x); }

__device__ __forceinline__ float tanhf_fast(float x) {
    float e = exp2f_fast(x * 2.885390081777927f);
    return 1.0f - 2.0f * rcpf_fast(1.0f + e);
}
__device__ __forceinline__ float sigmf_fast(float x) {
    float e = exp2f_fast(x * -1.4426950408889634f);
    return rcpf_fast(1.0f + e);
}

// Lane decomposition (16 lanes per batch element):
//   q  = lane bits {0,1}  : column-block (cols 8q..8q+7) / reduce dimension (DPP quads)
//   e  = lane bits {2,4}  : element-within-wave (4 elements per wave)
//   p  = lane bits {3,5}  : row-block (rows 8p..8p+7)
// Lane (p,q) holds W-block rows 8p+(j^off), cols 8q..8q+7 in registers; row perm
// off = (q0<<1)|(q1<<2) makes the XOR reduce-scatter placement-free: after rounds
// (xor2, xor1), P[0],P[1] hold full sums for components 2*(4p+q)+{0,1}.
//
// Spill forensics (r3/r4 counters): WRITE 890 MB = 435 f32/thread spill slots
// (written once); FETCH 8.9 GB = 156 f32 x 28 GRU reloads/thread (HBM-miss, the
// 912 MB spill footprint >> 32 MB L2). rk4 is spill-clean. Cause: scheduler
// hoists the GRU's LDS weight loads across gates, stacking ~100 extra live regs
// on top of w1/w2[128]. Fix: sched_barrier(0) fences between gates + b128 reads.
__global__ __launch_bounds__(256) __attribute__((amdgpu_waves_per_eu(2, 2)))
void node_kernel(
    const float* __restrict__ g_inputs, const float* __restrict__ g_h0,
    const float* __restrict__ g_Wih, const float* __restrict__ g_Whh,
    const float* __restrict__ g_bih, const float* __restrict__ g_bhh,
    const float* __restrict__ g_W1, const float* __restrict__ g_b1,
    const float* __restrict__ g_W2, const float* __restrict__ g_b2,
    float* __restrict__ g_out)
{
    // stride 36: float4-aligned; rows r and r+8 alias 2-way (free per m136)
    __shared__ __align__(16) float sWih[96 * 36];
    __shared__ __align__(16) float sWhh[96 * 36];

    const int tid = threadIdx.x;
    for (int i = tid; i < 96 * 32; i += 256) {
        int r = i >> 5, c = i & 31;
        sWih[r * 36 + c] = g_Wih[i];
        sWhh[r * 36 + c] = g_Whh[i];
    }
    __syncthreads();

    const int lane = tid & 63;
    const int wid = tid >> 6;
    const int q = lane & 3;
    const int q0 = q & 1, q1 = (q >> 1) & 1;
    const int p = ((lane >> 3) & 1) | (((lane >> 5) & 1) << 1);
    const int eloc = ((lane >> 2) & 1) | (((lane >> 4) & 1) << 1);
    const int elem = blockIdx.x * 16 + wid * 4 + eloc;
    const int off = (q0 << 1) | (q1 << 2);
    const int comp0 = ((p << 2) | q) << 1;   // owned components comp0, comp0+1

    // bpermute byte-indices: component 8q+2n+i lives on rank 4q+n
    int idx[4];
    {
        const int ebits = lane & 0x14;
        #pragma unroll
        for (int n = 0; n < 4; ++n) {
            int sl = n | (q0 << 3) | (q1 << 5) | ebits;
            idx[n] = sl << 2;
        }
    }

    // ODE MLP weights: entirely in registers (8x8 block per lane, row-permuted)
    float w1[8][8], w2[8][8];
    #pragma unroll
    for (int j = 0; j < 8; ++j) {
        const int row = 8 * p + (j ^ off);
        #pragma unroll
        for (int cb = 0; cb < 8; cb += 4) {
            float4 a = *reinterpret_cast<const float4*>(&g_W1[row * 32 + 8 * q + cb]);
            w1[j][cb] = a.x; w1[j][cb + 1] = a.y; w1[j][cb + 2] = a.z; w1[j][cb + 3] = a.w;
            float4 b = *reinterpret_cast<const float4*>(&g_W2[row * 32 + 8 * q + cb]);
            w2[j][cb] = b.x; w2[j][cb + 1] = b.y; w2[j][cb + 2] = b.z; w2[j][cb + 3] = b.w;
        }
    }

    const float b1o0 = g_b1[comp0], b1o1 = g_b1[comp0 + 1];
    const float b2o0 = g_b2[comp0], b2o1 = g_b2[comp0 + 1];
    const float br0 = g_bih[comp0] + g_bhh[comp0];
    const float br1 = g_bih[comp0 + 1] + g_bhh[comp0 + 1];
    const float bz0 = g_bih[32 + comp0] + g_bhh[32 + comp0];
    const float bz1 = g_bih[32 + comp0 + 1] + g_bhh[32 + comp0 + 1];
    const float bin0 = g_bih[64 + comp0], bin1 = g_bih[64 + comp0 + 1];
    const float bhn0 = g_bhh[64 + comp0], bhn1 = g_bhh[64 + comp0 + 1];

    float y0, y1;  // owned 2 components of hidden state
    {
        float2 h = *reinterpret_cast<const float2*>(&g_h0[(size_t)elem * 32 + comp0]);
        y0 = h.x; y1 = h.y;
    }

    auto gather8 = [&](float v0, float v1, float (&in)[8]) {
        #pragma unroll
        for (int n = 0; n < 4; ++n) {
            in[2 * n]     = bpermf(idx[n], v0);
            in[2 * n + 1] = bpermf(idx[n], v1);
        }
    };

    // XOR reduce-scatter over q (placement-free thanks to row perm `off`)
    auto reduceP = [&](float (&P)[8]) {
        P[0] += dppf<XOR2>(P[4]);
        P[1] += dppf<XOR2>(P[5]);
        P[2] += dppf<XOR2>(P[6]);
        P[3] += dppf<XOR2>(P[7]);
        P[0] += dppf<XOR1>(P[2]);
        P[1] += dppf<XOR1>(P[3]);
    };

    auto layer = [&](const float (&w)[8][8], const float (&in)[8], float& o0, float& o1) {
        float P[8];
        #pragma unroll
        for (int j = 0; j < 8; ++j) {
            float s = w[j][0] * in[0];
            #pragma unroll
            for (int cc = 1; cc < 8; ++cc) s = fmaf(w[j][cc], in[cc], s);
            P[j] = s;
        }
        reduceP(P);
        o0 = P[0]; o1 = P[1];
    };

    auto rhs = [&](float v0, float v1, float& k0, float& k1) {
        float in[8];
        gather8(v0, v1, in);
        float t0, t1;
        layer(w1, in, t0, t1);
        t0 = tanhf_fast(t0 + b1o0);
        t1 = tanhf_fast(t1 + b1o1);
        gather8(t0, t1, in);
        layer(w2, in, k0, k1);
        k0 += b2o0; k1 += b2o1;
    };

    auto rk4 = [&](float dt) {
        const float hdt = 0.5f * dt;
        const float sdt = dt * (1.0f / 6.0f);
        #pragma unroll 1
        for (int s = 0; s < 10; ++s) {
            float k0, k1, a0, a1, v0, v1;
            rhs(y0, y1, k0, k1);
            a0 = k0; a1 = k1;
            v0 = fmaf(hdt, k0, y0); v1 = fmaf(hdt, k1, y1);
            rhs(v0, v1, k0, k1);
            a0 = fmaf(2.0f, k0, a0); a1 = fmaf(2.0f, k1, a1);
            v0 = fmaf(hdt, k0, y0); v1 = fmaf(hdt, k1, y1);
            rhs(v0, v1, k0, k1);
            a0 = fmaf(2.0f, k0, a0); a1 = fmaf(2.0f, k1, a1);
            v0 = fmaf(dt, k0, y0); v1 = fmaf(dt, k1, y1);
            rhs(v0, v1, k0, k1);
            a0 += k0; a1 += k1;
            y0 = fmaf(sdt, a0, y0); y1 = fmaf(sdt, a1, y1);
        }
    };

    // One gate's (Wih.x + Whh.h) dot via ds_read_b128; reduce to 2 owned comps.
    auto gate_dot2 = [&](int gofs, const float (&xin)[8], const float (&hin)[8],
                         float& o0, float& o1) {
        float P[8];
        #pragma unroll
        for (int j = 0; j < 8; ++j) {
            const int row = gofs + 8 * p + (j ^ off);
            const float* wi = &sWih[row * 36 + 8 * q];
            const float* wh = &sWhh[row * 36 + 8 * q];
            float4 a0v = *reinterpret_cast<const float4*>(wi);
            float4 a1v = *reinterpret_cast<const float4*>(wi + 4);
            float4 h0v = *reinterpret_cast<const float4*>(wh);
            float4 h1v = *reinterpret_cast<const float4*>(wh + 4);
            float s;
            s = a0v.x * xin[0];
            s = fmaf(a0v.y, xin[1], s);
            s = fmaf(a0v.z, xin[2], s);
            s = fmaf(a0v.w, xin[3], s);
            s = fmaf(a1v.x, xin[4], s);
            s = fmaf(a1v.y, xin[5], s);
            s = fmaf(a1v.z, xin[6], s);
            s = fmaf(a1v.w, xin[7], s);
            s = fmaf(h0v.x, hin[0], s);
            s = fmaf(h0v.y, hin[1], s);
            s = fmaf(h0v.z, hin[2], s);
            s = fmaf(h0v.w, hin[3], s);
            s = fmaf(h1v.x, hin[4], s);
            s = fmaf(h1v.y, hin[5], s);
            s = fmaf(h1v.z, hin[6], s);
            s = fmaf(h1v.w, hin[7], s);
            P[j] = s;
        }
        reduceP(P);
        o0 = P[0]; o1 = P[1];
    };

    // Single-matrix gate dot (for the n gate's separate x / h parts)
    auto gate_dot1 = [&](const float* smat, int gofs, const float (&vin)[8],
                         float& o0, float& o1) {
        float P[8];
        #pragma unroll
        for (int j = 0; j < 8; ++j) {
            const int row = gofs + 8 * p + (j ^ off);
            const float* wr = &smat[row * 36 + 8 * q];
            float4 a0v = *reinterpret_cast<const float4*>(wr);
            float4 a1v = *reinterpret_cast<const float4*>(wr + 4);
            float s;
            s = a0v.x * vin[0];
            s = fmaf(a0v.y, vin[1], s);
            s = fmaf(a0v.z, vin[2], s);
            s = fmaf(a0v.w, vin[3], s);
            s = fmaf(a1v.x, vin[4], s);
            s = fmaf(a1v.y, vin[5], s);
            s = fmaf(a1v.z, vin[6], s);
            s = fmaf(a1v.w, vin[7], s);
            P[j] = s;
        }
        reduceP(P);
        o0 = P[0]; o1 = P[1];
    };

    // Sequential-gate GRU with sched_barrier fences: forbid the scheduler from
    // hoisting gate k+1's LDS loads over gate k (the r3/r4 spill driver).
    auto gru = [&](int t) {
        float xin[8];
        {
            const float* xp = &g_inputs[((size_t)elem * TSTEPS + t) * 32 + 8 * q];
            float4 xa = *reinterpret_cast<const float4*>(xp);
            float4 xb = *reinterpret_cast<const float4*>(xp + 4);
            xin[0] = xa.x; xin[1] = xa.y; xin[2] = xa.z; xin[3] = xa.w;
            xin[4] = xb.x; xin[5] = xb.y; xin[6] = xb.z; xin[7] = xb.w;
        }
        float hin[8];
        gather8(y0, y1, hin);
        __builtin_amdgcn_sched_barrier(0);

        float r0, r1, z0, z1, nx0, nx1, nh0, nh1;
        gate_dot2(0, xin, hin, r0, r1);
        r0 = sigmf_fast(r0 + br0);
        r1 = sigmf_fast(r1 + br1);
        __builtin_amdgcn_sched_barrier(0);
        gate_dot2(32, xin, hin, z0, z1);
        z0 = sigmf_fast(z0 + bz0);
        z1 = sigmf_fast(z1 + bz1);
        __builtin_amdgcn_sched_barrier(0);
        gate_dot1(sWih, 64, xin, nx0, nx1);
        __builtin_amdgcn_sched_barrier(0);
        gate_dot1(sWhh, 64, hin, nh0, nh1);
        __builtin_amdgcn_sched_barrier(0);
        float n0 = tanhf_fast(nx0 + bin0 + r0 * (nh0 + bhn0));
        float n1 = tanhf_fast(nx1 + bin1 + r1 * (nh1 + bhn1));
        y0 = n0 + z0 * (y0 - n0);
        y1 = n1 + z1 * (y1 - n1);
    };

    // initial integration over [0,1]
    rk4(0.1f);
    #pragma unroll 1
    for (int t = 0; t < TSTEPS - 1; ++t) {
        gru(t);
        rk4(0.1f);
    }
    gru(TSTEPS - 1);
    {
        float2 hs;
        hs.x = fmaxf(y0, 0.f); hs.y = fmaxf(y1, 0.f);
        *reinterpret_cast<float2*>(&g_out[(size_t)elem * 32 + comp0]) = hs;
    }
    rk4(1.4f);  // span 14 -> dt 1.4
    {
        float2 he;
        he.x = fmaxf(y0, 0.f); he.y = fmaxf(y1, 0.f);
        *reinterpret_cast<float2*>(&g_out[(size_t)BATCH * 32 + (size_t)elem * 32 + comp0]) = he;
    }
}

}  // namespace

extern "C" void kernel_launch(void* const* d_in, const int* in_sizes, int n_in,
                              void* d_out, int out_size, void* d_ws, size_t ws_size,
                              hipStream_t stream) {
    (void)in_sizes; (void)n_in; (void)out_size; (void)d_ws; (void)ws_size;
    const float* inputs = (const float*)d_in[0];
    const float* h0     = (const float*)d_in[1];
    const float* Wih    = (const float*)d_in[2];
    const float* Whh    = (const float*)d_in[3];
    const float* bih    = (const float*)d_in[4];
    const float* bhh    = (const float*)d_in[5];
    const float* W1     = (const float*)d_in[6];
    const float* b1     = (const float*)d_in[7];
    const float* W2     = (const float*)d_in[8];
    const float* b2     = (const float*)d_in[9];
    float* out = (float*)d_out;

    dim3 grid(BATCH / 16);   // 16 elements per 256-thread block (16 lanes/element)
    dim3 block(256);
    hipLaunchKernelGGL(node_kernel, grid, block, 0, stream,
                       inputs, h0, Wih, Whh, bih, bhh, W1, b1, W2, b2, out);
}